// Round 9
// baseline (501.648 us; speedup 1.0000x reference)
//
#include <hip/hip_runtime.h>

// B=1024, H=56, J=64, N=56, I=64.
// t4[b,i,m,n] = sum_{k,j} x[b, m+k-1, j, n] * W2[i,k,j]   (zero-padded in h)
// y[b,i,m,(n+1)%56] = t4[b,i,m,n]*W1[i,0] + t4[b,i,(m-1)%56,n]*W1[i,1]
//
// Folded 4-tap: y[i,m,c] = sum_{k'} W2'[i,k',j] * x[m-2+k', j, (c-1)%56]
//   W2' = [bW0, aW0+bW1, aW1+bW2, aW2]  (boundary taps skipped);
//   m=0 wrap uses W2'' = [bW0, bW1, aW1, aW2] over x54,x55,x0,x1.
//
// ROLLING structure: loop h=0..55; slice h read ONCE feeds rows m=h-1..h+2
// (k' = h-m+2) -> 4:1 MFMA:ds_read. Block = (batch, i-quarter), all 56 cols:
// staging is contiguous 14KB slices; stores are m-sequential 12.5KB streams
// per i-row, full 64B sectors (n-roll folded into B-row rotation).
// 4 sibling blocks share x[batch] via one XCD (bid&7 swizzle, 822KB < L2).

#define SLICE 4032   // ushorts per slice: 56 rows * 72 (144B padded rows)

typedef __attribute__((ext_vector_type(8))) short short8_t;
typedef __attribute__((ext_vector_type(4))) short short4_t;
typedef __attribute__((ext_vector_type(4))) float f32x4;

__device__ __forceinline__ unsigned short f2bf(float f) {
  union { float f; unsigned u; } v; v.f = f;
  return (unsigned short)((v.u + 0x7FFFu + ((v.u >> 16) & 1u)) >> 16);
}

#define BARRIER() do {                                   \
    asm volatile("s_waitcnt lgkmcnt(0)" ::: "memory");   \
    __builtin_amdgcn_s_barrier();                        \
  } while (0)

// ---- pre-kernel: merged 4-tap weight sets (bf16) into ws ----
__global__ void prep_weights(const float* __restrict__ W1,
                             const float* __restrict__ W2,
                             unsigned short* __restrict__ wp) {
  const int t = threadIdx.x;            // 256 threads
  const int i = t >> 2;
  const int j0 = (t & 3) * 16;
  const float a = W1[i * 2 + 0], b = W1[i * 2 + 1];
  const float* w = W2 + i * 192;
  unsigned short* p0 = wp + i * 256;            // W2'  (rolling)
  unsigned short* p1 = wp + 16384 + i * 256;    // W2'' (m = 0 wrap)
  for (int j = j0; j < j0 + 16; ++j) {
    const float w0 = w[j], w1 = w[64 + j], w2 = w[128 + j];
    p0[j]       = f2bf(b * w0);
    p0[64 + j]  = f2bf(a * w0 + b * w1);
    p0[128 + j] = f2bf(a * w1 + b * w2);
    p0[192 + j] = f2bf(a * w2);
    p1[j]       = f2bf(b * w0);
    p1[64 + j]  = f2bf(b * w1);
    p1[128 + j] = f2bf(a * w1);
    p1[192 + j] = f2bf(a * w2);
  }
}

__global__ __launch_bounds__(256, 4) void conv_roll(
    const float* __restrict__ x, const unsigned short* __restrict__ wp,
    float* __restrict__ out) {
  __shared__ unsigned short lds[4 * SLICE];   // 32256 B -> 4 blocks/CU

  const int tid = threadIdx.x;
  const int ct  = tid >> 6;           // wave = col tile (0..3)
  const int lq  = tid & 15;
  const int lg  = (tid >> 4) & 3;

  // bijective swizzle: 4 sibling blocks of a batch share one XCD (bid&7)
  const int bid = blockIdx.x;
  const int k = bid >> 3;
  const int batch = (bid & 7) * 128 + (k >> 2);
  const int iq = k & 3;               // i-quarter: rows 16*iq..+15

  const float* __restrict__ xb = x + (size_t)batch * 200704;  // 56*64*56

  // ---- A fragments: W2' (64 x 256 bf16), i = 16*iq + lq ----
  short8_t af[8];
  const unsigned short* ap = wp + ((16 * iq + lq) << 8) + lg * 8;
  #pragma unroll
  for (int s = 0; s < 8; ++s) af[s] = *(const short8_t*)(ap + s * 32);
  const unsigned short* wpp = wp + 16384 + ((16 * iq + lq) << 8) + lg * 8;

  // ---- B row base: col c = 16*ct + lq reads source row (c+55)%56 ----
  const int c = 16 * ct + lq;
  const int rbase = ((c + 55) % 56) * 72 + lg * 8;   // + slot*SLICE + 32*s

  // ---- output: i = 16*iq + 4*lg + r, col c; m-sequential streams ----
  float* const outp = out + ((size_t)batch * 64 + 16 * iq + 4 * lg) * 3136 + c;
  const bool act = c < 56;

  // ---- staging: 224 workers = j-quad(16) x n-quad(14); contiguous loads ----
  const bool stg = tid < 224;
  const int j4 = tid / 14, n4 = tid % 14;
  const float* const xsrc = xb + (size_t)(4 * j4) * 56 + 4 * n4;
  unsigned short* const wbase = &lds[(size_t)(4 * n4) * 72 + 4 * j4];

  float4 Ra[4], Rb[4];
  auto issue = [&](int h, float4* R) {
    if (stg && h < 56) {
      const float* p = xsrc + (size_t)h * 3584;
      R[0] = *(const float4*)(p);
      R[1] = *(const float4*)(p + 56);
      R[2] = *(const float4*)(p + 112);
      R[3] = *(const float4*)(p + 168);
    }
  };
  auto putS = [&](int slot, const float4* R) {   // transpose 4x4, b64 writes
    if (stg) {
      unsigned short* wb = wbase + slot * SLICE;
      short4_t v;
      v[0] = (short)f2bf(R[0].x); v[1] = (short)f2bf(R[1].x);
      v[2] = (short)f2bf(R[2].x); v[3] = (short)f2bf(R[3].x);
      *(short4_t*)(wb) = v;
      v[0] = (short)f2bf(R[0].y); v[1] = (short)f2bf(R[1].y);
      v[2] = (short)f2bf(R[2].y); v[3] = (short)f2bf(R[3].y);
      *(short4_t*)(wb + 72) = v;
      v[0] = (short)f2bf(R[0].z); v[1] = (short)f2bf(R[1].z);
      v[2] = (short)f2bf(R[2].z); v[3] = (short)f2bf(R[3].z);
      *(short4_t*)(wb + 144) = v;
      v[0] = (short)f2bf(R[0].w); v[1] = (short)f2bf(R[1].w);
      v[2] = (short)f2bf(R[2].w); v[3] = (short)f2bf(R[3].w);
      *(short4_t*)(wb + 216) = v;
    }
  };

  f32x4 acc[4], m0acc;
  #pragma unroll
  for (int s = 0; s < 4; ++s) acc[s] = (f32x4){0.f, 0.f, 0.f, 0.f};
  m0acc = (f32x4){0.f, 0.f, 0.f, 0.f};
  short8_t b0, b1;

  auto readB = [&](int slot) {
    b0 = *(const short8_t*)&lds[slot * SLICE + rbase];
    b1 = *(const short8_t*)&lds[slot * SLICE + rbase + 32];
  };
  auto tap = [&](f32x4& a, int kp) {
    a = __builtin_amdgcn_mfma_f32_16x16x32_bf16(af[2 * kp], b0, a, 0, 0, 0);
    a = __builtin_amdgcn_mfma_f32_16x16x32_bf16(af[2 * kp + 1], b1, a, 0, 0, 0);
  };
  auto tapW = [&](int s2) {   // W'' frag pair s2, s2+1 into m0acc
    const short8_t w0 = *(const short8_t*)(wpp + s2 * 32);
    const short8_t w1 = *(const short8_t*)(wpp + s2 * 32 + 32);
    m0acc = __builtin_amdgcn_mfma_f32_16x16x32_bf16(w0, b0, m0acc, 0, 0, 0);
    m0acc = __builtin_amdgcn_mfma_f32_16x16x32_bf16(w1, b1, m0acc, 0, 0, 0);
  };
  auto storeRow = [&](int m, const f32x4& a) {
    if (act) {
      float* pm = outp + m * 56;
      #pragma unroll
      for (int r = 0; r < 4; ++r) pm[(size_t)r * 3136] = a[r];
    }
  };

  // ---- prologue: stage slices 0,1; prime depth-2 (2,3 in flight) ----
  issue(0, Ra); putS(0, Ra);
  issue(1, Rb); putS(1, Rb);
  issue(2, Ra); issue(3, Rb);
  BARRIER();

  // ---- peel h=0: rows m=2(k'0), 1(k'1), 0(W''2) ----
  readB(0);
  tap(acc[2], 0); tap(acc[1], 1); tapW(4);
  putS(2, Ra); issue(4, Ra);
  BARRIER();
  // ---- peel h=1: rows 3(k'0), 2(k'1), 1(k'2), 0(W''3) ----
  readB(1);
  tap(acc[3], 0); tap(acc[2], 1); tap(acc[1], 2); tapW(6);
  putS(3, Rb); issue(5, Rb);
  BARRIER();

  // ---- main: h = 2..53, 13 iters x 4 substeps (all slots static) ----
  // step h (h = 2+d mod 4): read slice slot h&3; rows m=h+2..h-1 get
  // k'=0..3; store row h-1; putS slice h+2 -> slot d; issue slice h+4.
#define STEP(HH, D)                                                        \
  do {                                                                     \
    readB((2 + (D)) & 3);                                                  \
    tap(acc[(D)], 0);                                                      \
    tap(acc[(3 + (D)) & 3], 1);                                            \
    tap(acc[(2 + (D)) & 3], 2);                                            \
    tap(acc[(1 + (D)) & 3], 3);                                            \
    putS((D), ((D) & 1) ? Rb : Ra);                                        \
    issue((HH) + 4, ((D) & 1) ? Rb : Ra);                                  \
    storeRow((HH) - 1, acc[(1 + (D)) & 3]);                                \
    acc[(1 + (D)) & 3] = (f32x4){0.f, 0.f, 0.f, 0.f};                      \
    BARRIER();                                                             \
  } while (0)

  #pragma unroll 1
  for (int u = 0; u < 13; ++u) {
    const int h = 2 + 4 * u;
    STEP(h, 0);
    STEP(h + 1, 1);
    STEP(h + 2, 2);
    STEP(h + 3, 3);
  }
#undef STEP

  // ---- peel h=54: rows 55(k'1), 54(k'2), 53(k'3), 0(W''0); store 53 ----
  readB(2);
  tap(acc[3], 1); tap(acc[2], 2); tap(acc[1], 3); tapW(0);
  storeRow(53, acc[1]);
  BARRIER();
  // ---- peel h=55: rows 55(k'2), 54(k'3), 0(W''1); store 54,55,0 ----
  readB(3);
  tap(acc[3], 2); tap(acc[2], 3); tapW(2);
  storeRow(54, acc[2]);
  storeRow(55, acc[3]);
  storeRow(0, m0acc);
}

extern "C" void kernel_launch(void* const* d_in, const int* in_sizes, int n_in,
                              void* d_out, int out_size, void* d_ws, size_t ws_size,
                              hipStream_t stream) {
  const float* x  = (const float*)d_in[0];
  const float* W1 = (const float*)d_in[1];
  const float* W2 = (const float*)d_in[2];
  float* out = (float*)d_out;
  unsigned short* wp = (unsigned short*)d_ws;
  prep_weights<<<1, 256, 0, stream>>>(W1, W2, wp);
  conv_roll<<<4096, 256, 0, stream>>>(x, wp, out);
}